// Round 1
// 4459.125 us; speedup vs baseline: 1.3162x; 1.3162x over previous
//
#include <hip/hip_runtime.h>
#include <hip/hip_cooperative_groups.h>

// LSTM: B=64, T=256, IN=512, H=1024 (4H=4096), OUT=512. I/O f32.
// Round-11 = round-10 source with ONE structural change: remove ALL
// agent-RELEASE orderings (each forced a buffer_wbl2 = full 4MB L2
// writeback, 32 concurrent per XCD per step -> theory: the ~18us/step
// of unmodeled barrier cost; r9->r10 poll change was null because the
// ACQ_REL arrival RMWs were identical).
//   - h is published via write-through L2-bypass stores
//     (global_store_short sc0 sc1): data is at LLC (agent coherence
//     point) once vmcnt drains, which __syncthreads already does.
//   - barrier arrival RMWs demoted ACQ_REL -> RELAXED (plain
//     global_atomic_add sc1, no cache ops).
//   - keep exactly ONE acquire fence (buffer_inv) per block per step
//     after spin exit so the CACHED h loads in phase A see fresh LLC
//     data (keeps h broadcast through L2: FETCH ~2MB/step, not a
//     64MB/step LLC bypass flood). r9 proved inv is cheap.
// Visibility chain: h stores (sc0 sc1) -> vmcnt(0) at __syncthreads ->
// cnt8 relaxed RMW at LLC -> leader observes 32 arrivals -> root RMW ->
// consumers poll root -> acquire fence (inv) -> cached h loads fresh.
// Compute path identical to r5/r6/r9/r10 (absmax 7.8e-3).

#define B_   64
#define T_   256
#define IN_  512
#define H_   1024
#define G4_  4096
#define OUT_ 512
#define KTOT 1536   // IN_ + H_

typedef __bf16 bf8v  __attribute__((ext_vector_type(8)));
typedef float  f4v   __attribute__((ext_vector_type(4)));

__device__ __forceinline__ float sigm(float x) { return 1.f / (1.f + __expf(-x)); }
__device__ __forceinline__ float tanh_f(float x) { return 1.f - 2.f / (__expf(2.f * x) + 1.f); }

// Write-through store of one bf16, bypassing L1 (sc0) and L2 (sc1):
// value is visible at the LLC (agent coherence point) when vmcnt retires.
__device__ __forceinline__ void store_bf16_wt(__bf16* p, __bf16 v) {
    union { __bf16 b; unsigned short s; } cv; cv.b = v;
    unsigned w = cv.s;
    asm volatile("global_store_short %0, %1, off sc0 sc1"
                 :: "v"(p), "v"(w) : "memory");
}

// Monotonic all-block barrier. cnt8[g] at cnt8[g*32] (one 128B line each);
// root on its own line. t-th use: cnt -> 32*(t+1), root -> 8*(t+1).
// All RMWs RELAXED (no wbl2/inv); one acquire fence (inv) on exit.
__device__ __forceinline__ void grid_barrier(unsigned* cnt8, unsigned* root,
                                             int t, int blk) {
    __syncthreads();   // drains vmcnt: all waves' sc0sc1 h stores ack'd at LLC
    if (threadIdx.x == 0) {
        unsigned a = __hip_atomic_fetch_add(&cnt8[(blk & 7) * 32], 1u,
                                            __ATOMIC_RELAXED, __HIP_MEMORY_SCOPE_AGENT);
        if (a == 32u * (unsigned)(t + 1) - 1u)   // last arriver of this sub-group
            __hip_atomic_fetch_add(root, 1u,
                                   __ATOMIC_RELAXED, __HIP_MEMORY_SCOPE_AGENT);
        const unsigned tgt = 8u * (unsigned)(t + 1);
        int spins = 0;
        while (__hip_atomic_load(root, __ATOMIC_RELAXED,
                                 __HIP_MEMORY_SCOPE_AGENT) < tgt) {   // sc1: fresh
            __builtin_amdgcn_s_sleep(2);
            if ((++spins & 63) == 0 &&
                __hip_atomic_load(root, __ATOMIC_ACQUIRE,
                                  __HIP_MEMORY_SCOPE_AGENT) >= tgt)   // progress hedge
                break;
        }
        __builtin_amdgcn_fence(__ATOMIC_ACQUIRE, "agent");   // one inv: h visible to cached loads
    }
    __syncthreads();
}

__global__ void __launch_bounds__(256)
lstm_fused(const float* __restrict__ xs, const float* __restrict__ Wi,
           const float* __restrict__ Wh, const float* __restrict__ bias,
           const float* __restrict__ Wo, const float* __restrict__ bo,
           float* __restrict__ out, __bf16* __restrict__ hws,
           unsigned* __restrict__ cnt8, unsigned* __restrict__ root)
{
    __shared__ __bf16 Wlds[16][KTOT + 8];   // ~48.3 KB (bf16-rounded weights)
    __shared__ float  gbuf[64][17];         // 4.3 KB
    __shared__ float  obuf[4][16][17];      // 4.3 KB   (total ~57 KB)

    const int tid = threadIdx.x;
    const int blk = blockIdx.x;       // 0..255
    const int j0  = blk * 4;
    const int ob0 = (blk >> 5) * 8;   // out-proj batch group (8 batches)
    const int oc0 = (blk & 31) * 16;  // out-proj col group (16 cols)

    // Stage resident gate-weight slab (f32 -> bf16)
    for (int idx = tid; idx < 16 * KTOT; idx += 256) {
        int k = idx >> 4, c = idx & 15;
        int gc = (c >> 2) * H_ + j0 + (c & 3);
        float w = (k < IN_) ? Wi[(size_t)k * G4_ + gc]
                            : Wh[(size_t)(k - IN_) * G4_ + gc];
        Wlds[c][k] = (__bf16)w;
    }
    __syncthreads();

    const int lane = tid & 63;
    const int wave = tid >> 6;
    const int c    = lane & 15;
    const int quad = lane >> 4;
    const int rowA = wave * 16 + c;   // batch row for gate A-frags
    const int kq   = quad * 8;

    const float biasv = bias[(c >> 2) * H_ + j0 + (c & 3)];

    // Hoist step-invariant Wo fragments into registers (f32 -> bf16)
    bf8v wof[8];
    #pragma unroll
    for (int kk = 0; kk < 8; ++kk) {
        int kbase = wave * 256 + kk * 32 + kq;
        #pragma unroll
        for (int j = 0; j < 8; ++j)
            wof[kk][j] = (__bf16)Wo[(size_t)(kbase + j) * OUT_ + oc0 + c];
    }

    // recurrent cell state: thread owns (batch = tid>>2, j = j0 + (tid&3))
    float c_reg = 0.f;
    const int bb = tid >> 2;
    const int jo = tid & 3;

    // h ws layout: [buf(2)][part hi/lo][B][H] bf16
    for (int t = 0; t < T_; ++t) {
        const __bf16* hhi_p = hws + (size_t)(t & 1) * (2 * B_ * H_);
        const __bf16* hlo_p = hhi_p + B_ * H_;
        __bf16* hhi_c = hws + (size_t)((t + 1) & 1) * (2 * B_ * H_);
        __bf16* hlo_c = hhi_c + B_ * H_;

        // ---- phase A: gate MFMA for step t ----
        f4v acc0 = {0.f, 0.f, 0.f, 0.f};   // hi-product chain
        f4v acc1 = {0.f, 0.f, 0.f, 0.f};   // lo-product chain
        const float* xrow = xs + ((size_t)rowA * T_ + t) * IN_ + kq;
        #pragma unroll
        for (int ks = 0; ks < 16; ++ks) {
            f4v v0 = *(const f4v*)(xrow + ks * 32);
            f4v v1 = *(const f4v*)(xrow + ks * 32 + 4);
            bf8v ah, al;
            #pragma unroll
            for (int j = 0; j < 4; ++j) {
                __bf16 h0 = (__bf16)v0[j], h1 = (__bf16)v1[j];
                ah[j] = h0;  ah[4 + j] = h1;
                al[j]     = (__bf16)(v0[j] - (float)h0);
                al[4 + j] = (__bf16)(v1[j] - (float)h1);
            }
            bf8v w = *(const bf8v*)&Wlds[c][ks * 32 + kq];
            acc0 = __builtin_amdgcn_mfma_f32_16x16x32_bf16(ah, w, acc0, 0, 0, 0);
            acc1 = __builtin_amdgcn_mfma_f32_16x16x32_bf16(al, w, acc1, 0, 0, 0);
        }
        if (t > 0) {
            const __bf16* hh = hhi_p + (size_t)rowA * H_ + kq;
            const __bf16* hl = hlo_p + (size_t)rowA * H_ + kq;
            #pragma unroll
            for (int ks = 0; ks < 32; ++ks) {
                bf8v ah = *(const bf8v*)(hh + ks * 32);
                bf8v al = *(const bf8v*)(hl + ks * 32);
                bf8v w  = *(const bf8v*)&Wlds[c][IN_ + ks * 32 + kq];
                acc0 = __builtin_amdgcn_mfma_f32_16x16x32_bf16(ah, w, acc0, 0, 0, 0);
                acc1 = __builtin_amdgcn_mfma_f32_16x16x32_bf16(al, w, acc1, 0, 0, 0);
            }
        }
        f4v acc = acc0 + acc1;
        #pragma unroll
        for (int r = 0; r < 4; ++r)
            gbuf[wave * 16 + quad * 4 + r][c] = acc[r] + biasv;  // C: col=c, row=quad*4+r

        // ---- phase A2: out-proj partial for step t-1 (reads same h_{t-1}) ----
        if (t > 0) {
            f4v oac = {0.f, 0.f, 0.f, 0.f};
            #pragma unroll
            for (int kk = 0; kk < 8; ++kk) {
                int kbase = wave * 256 + kk * 32 + kq;
                bf8v ah = {}, al = {};
                if (c < 8) {   // A rows 8..15 zero (8 batches per tile)
                    ah = *(const bf8v*)&hhi_p[(size_t)(ob0 + c) * H_ + kbase];
                    al = *(const bf8v*)&hlo_p[(size_t)(ob0 + c) * H_ + kbase];
                }
                oac = __builtin_amdgcn_mfma_f32_16x16x32_bf16(ah, wof[kk], oac, 0, 0, 0);
                oac = __builtin_amdgcn_mfma_f32_16x16x32_bf16(al, wof[kk], oac, 0, 0, 0);
            }
            #pragma unroll
            for (int r = 0; r < 4; ++r)
                obuf[wave][quad * 4 + r][c] = oac[r];
        }
        __syncthreads();

        // ---- phase B: elementwise cell update, write h_t (hi+lo, write-through) ----
        {
            float gi = gbuf[bb][jo];
            float gf = gbuf[bb][4 + jo];
            float gg = gbuf[bb][8 + jo];
            float go = gbuf[bb][12 + jo];
            c_reg = sigm(gf) * c_reg + sigm(gi) * tanh_f(gg);
            float hn = sigm(go) * tanh_f(c_reg);
            __bf16 hh = (__bf16)hn;
            store_bf16_wt(&hhi_c[(size_t)bb * H_ + j0 + jo], hh);
            store_bf16_wt(&hlo_c[(size_t)bb * H_ + j0 + jo], (__bf16)(hn - (float)hh));
        }
        // ---- phase B2: reduce out-proj partials, store out[:, t-1, :] ----
        if (t > 0 && tid < 128) {
            int m = tid >> 4, cc = tid & 15;
            float v = obuf[0][m][cc] + obuf[1][m][cc] + obuf[2][m][cc] + obuf[3][m][cc]
                    + bo[oc0 + cc];
            out[(((size_t)(ob0 + m)) * T_ + (t - 1)) * OUT_ + oc0 + cc] = v;
        }

        grid_barrier(cnt8, root, t, blk);   // publish h_t; guards gbuf/obuf WAR
    }

    // ---- epilogue: out-proj for t = T-1 (h_{T-1} is in buffer 0; T even) ----
    {
        const __bf16* hhi_l = hws;
        const __bf16* hlo_l = hws + B_ * H_;
        f4v oac = {0.f, 0.f, 0.f, 0.f};
        #pragma unroll
        for (int kk = 0; kk < 8; ++kk) {
            int kbase = wave * 256 + kk * 32 + kq;
            bf8v ah = {}, al = {};
            if (c < 8) {
                ah = *(const bf8v*)&hhi_l[(size_t)(ob0 + c) * H_ + kbase];
                al = *(const bf8v*)&hlo_l[(size_t)(ob0 + c) * H_ + kbase];
            }
            oac = __builtin_amdgcn_mfma_f32_16x16x32_bf16(ah, wof[kk], oac, 0, 0, 0);
            oac = __builtin_amdgcn_mfma_f32_16x16x32_bf16(al, wof[kk], oac, 0, 0, 0);
        }
        #pragma unroll
        for (int r = 0; r < 4; ++r)
            obuf[wave][quad * 4 + r][c] = oac[r];
        __syncthreads();
        if (tid < 128) {
            int m = tid >> 4, cc = tid & 15;
            float v = obuf[0][m][cc] + obuf[1][m][cc] + obuf[2][m][cc] + obuf[3][m][cc]
                    + bo[oc0 + cc];
            out[(((size_t)(ob0 + m)) * T_ + (T_ - 1)) * OUT_ + oc0 + cc] = v;
        }
    }
}

extern "C" void kernel_launch(void* const* d_in, const int* in_sizes, int n_in,
                              void* d_out, int out_size, void* d_ws, size_t ws_size,
                              hipStream_t stream) {
    const float* xs = (const float*)d_in[0];
    const float* Wi = (const float*)d_in[1];
    const float* Wh = (const float*)d_in[2];
    const float* b  = (const float*)d_in[3];
    const float* Wo = (const float*)d_in[4];
    const float* bo = (const float*)d_in[5];
    float* out = (float*)d_out;

    // ws layout: [0,4K) barrier counters (line-padded, zeroed); [64K,+512K) h
    unsigned* cnt8 = (unsigned*)d_ws;          // 8 counters at cnt8[g*32]
    unsigned* root = cnt8 + 256;               // byte 1024: own 128B line
    __bf16*   hws  = (__bf16*)((char*)d_ws + 65536);

    hipMemsetAsync(d_ws, 0, 4096, stream);     // reset barrier counters (captured)

    void* args[] = {(void*)&xs, (void*)&Wi, (void*)&Wh, (void*)&b,
                    (void*)&Wo, (void*)&bo, (void*)&out, (void*)&hws,
                    (void*)&cnt8, (void*)&root};
    hipLaunchCooperativeKernel((void*)lstm_fused, dim3(256), dim3(256), args, 0, stream);
}

// Round 2
// 4237.415 us; speedup vs baseline: 1.3850x; 1.0523x over previous
//
#include <hip/hip_runtime.h>
#include <hip/hip_cooperative_groups.h>

// LSTM: B=64, T=256, IN=512, H=1024 (4H=4096), OUT=512. I/O f32.
// Round-12 = round-11 source with ONE structural change: replace the
// atomic-tree arrival (32 same-line fetch_adds per shard, serialized
// RMWs at the LLC ~200ns each => ~6-7us/step, the unexplained gap)
// with a FLAG-VECTOR barrier:
//   - arrival: each block stores flags[blk*16] = t+1 (write-through
//     sc0 sc1, independent store, NO serialization).
//   - wait: wave 0 polls all 256 flags (64 lanes x 4 relaxed agent
//     loads, 64B-padded) until __all(flags >= t+1). No master hop.
//   - exit: one acquire fence (buffer_inv) per block per step, as in
//     r11, so cached h loads see fresh LLC data.
// Flags are monotonic (t+1): no reset hazard; skew bound identical to
// the old barrier (a block exits only after ALL blocks arrived, so the
// h double-buffer WAR argument is unchanged).
// Visibility chain: h stores (sc0 sc1) -> vmcnt(0) at __syncthreads ->
// flag store (sc0 sc1) -> pollers see flag at LLC -> acquire fence ->
// cached h loads fresh.
// Compute path identical to r5/r6/r9/r10/r11 (absmax 7.8e-3).

#define B_   64
#define T_   256
#define IN_  512
#define H_   1024
#define G4_  4096
#define OUT_ 512
#define KTOT 1536   // IN_ + H_

typedef __bf16 bf8v  __attribute__((ext_vector_type(8)));
typedef float  f4v   __attribute__((ext_vector_type(4)));

__device__ __forceinline__ float sigm(float x) { return 1.f / (1.f + __expf(-x)); }
__device__ __forceinline__ float tanh_f(float x) { return 1.f - 2.f / (__expf(2.f * x) + 1.f); }

// Write-through store of one bf16, bypassing L1 (sc0) and L2 (sc1):
// value is visible at the LLC (agent coherence point) when vmcnt retires.
__device__ __forceinline__ void store_bf16_wt(__bf16* p, __bf16 v) {
    union { __bf16 b; unsigned short s; } cv; cv.b = v;
    unsigned w = cv.s;
    asm volatile("global_store_short %0, %1, off sc0 sc1"
                 :: "v"(p), "v"(w) : "memory");
}

// Flag-vector all-block barrier. flags[i*16] (64B apart), monotonic.
// t-th use: every flag reaches t+1. Arrival = one independent
// write-through store; wait = wave-0 polls all 256 flags directly.
__device__ __forceinline__ void grid_barrier(unsigned* flags, int t, int blk) {
    __syncthreads();   // drains vmcnt: all waves' sc0sc1 h stores ack'd at LLC
    const unsigned tgt = (unsigned)(t + 1);
    if (threadIdx.x < 64) {
        if (threadIdx.x == 0) {
            unsigned* p = &flags[blk * 16];
            asm volatile("global_store_dword %0, %1, off sc0 sc1"
                         :: "v"(p), "v"(tgt) : "memory");
        }
        const int lane = threadIdx.x;
        for (;;) {
            unsigned m0 = __hip_atomic_load(&flags[(lane * 4 + 0) * 16],
                                            __ATOMIC_RELAXED, __HIP_MEMORY_SCOPE_AGENT);
            unsigned m1 = __hip_atomic_load(&flags[(lane * 4 + 1) * 16],
                                            __ATOMIC_RELAXED, __HIP_MEMORY_SCOPE_AGENT);
            unsigned m2 = __hip_atomic_load(&flags[(lane * 4 + 2) * 16],
                                            __ATOMIC_RELAXED, __HIP_MEMORY_SCOPE_AGENT);
            unsigned m3 = __hip_atomic_load(&flags[(lane * 4 + 3) * 16],
                                            __ATOMIC_RELAXED, __HIP_MEMORY_SCOPE_AGENT);
            bool ok = (m0 >= tgt) & (m1 >= tgt) & (m2 >= tgt) & (m3 >= tgt);
            if (__all(ok)) break;
            __builtin_amdgcn_s_sleep(1);   // ~64cy backoff: cut LLC poll pressure
        }
        __builtin_amdgcn_fence(__ATOMIC_ACQUIRE, "agent");   // one inv: h visible to cached loads
    }
    __syncthreads();
}

__global__ void __launch_bounds__(256)
lstm_fused(const float* __restrict__ xs, const float* __restrict__ Wi,
           const float* __restrict__ Wh, const float* __restrict__ bias,
           const float* __restrict__ Wo, const float* __restrict__ bo,
           float* __restrict__ out, __bf16* __restrict__ hws,
           unsigned* __restrict__ flags)
{
    __shared__ __bf16 Wlds[16][KTOT + 8];   // ~48.3 KB (bf16-rounded weights)
    __shared__ float  gbuf[64][17];         // 4.3 KB
    __shared__ float  obuf[4][16][17];      // 4.3 KB   (total ~57 KB)

    const int tid = threadIdx.x;
    const int blk = blockIdx.x;       // 0..255
    const int j0  = blk * 4;
    const int ob0 = (blk >> 5) * 8;   // out-proj batch group (8 batches)
    const int oc0 = (blk & 31) * 16;  // out-proj col group (16 cols)

    // Stage resident gate-weight slab (f32 -> bf16)
    for (int idx = tid; idx < 16 * KTOT; idx += 256) {
        int k = idx >> 4, c = idx & 15;
        int gc = (c >> 2) * H_ + j0 + (c & 3);
        float w = (k < IN_) ? Wi[(size_t)k * G4_ + gc]
                            : Wh[(size_t)(k - IN_) * G4_ + gc];
        Wlds[c][k] = (__bf16)w;
    }
    __syncthreads();

    const int lane = tid & 63;
    const int wave = tid >> 6;
    const int c    = lane & 15;
    const int quad = lane >> 4;
    const int rowA = wave * 16 + c;   // batch row for gate A-frags
    const int kq   = quad * 8;

    const float biasv = bias[(c >> 2) * H_ + j0 + (c & 3)];

    // Hoist step-invariant Wo fragments into registers (f32 -> bf16)
    bf8v wof[8];
    #pragma unroll
    for (int kk = 0; kk < 8; ++kk) {
        int kbase = wave * 256 + kk * 32 + kq;
        #pragma unroll
        for (int j = 0; j < 8; ++j)
            wof[kk][j] = (__bf16)Wo[(size_t)(kbase + j) * OUT_ + oc0 + c];
    }

    // recurrent cell state: thread owns (batch = tid>>2, j = j0 + (tid&3))
    float c_reg = 0.f;
    const int bb = tid >> 2;
    const int jo = tid & 3;

    // h ws layout: [buf(2)][part hi/lo][B][H] bf16
    for (int t = 0; t < T_; ++t) {
        const __bf16* hhi_p = hws + (size_t)(t & 1) * (2 * B_ * H_);
        const __bf16* hlo_p = hhi_p + B_ * H_;
        __bf16* hhi_c = hws + (size_t)((t + 1) & 1) * (2 * B_ * H_);
        __bf16* hlo_c = hhi_c + B_ * H_;

        // ---- phase A: gate MFMA for step t ----
        f4v acc0 = {0.f, 0.f, 0.f, 0.f};   // hi-product chain
        f4v acc1 = {0.f, 0.f, 0.f, 0.f};   // lo-product chain
        const float* xrow = xs + ((size_t)rowA * T_ + t) * IN_ + kq;
        #pragma unroll
        for (int ks = 0; ks < 16; ++ks) {
            f4v v0 = *(const f4v*)(xrow + ks * 32);
            f4v v1 = *(const f4v*)(xrow + ks * 32 + 4);
            bf8v ah, al;
            #pragma unroll
            for (int j = 0; j < 4; ++j) {
                __bf16 h0 = (__bf16)v0[j], h1 = (__bf16)v1[j];
                ah[j] = h0;  ah[4 + j] = h1;
                al[j]     = (__bf16)(v0[j] - (float)h0);
                al[4 + j] = (__bf16)(v1[j] - (float)h1);
            }
            bf8v w = *(const bf8v*)&Wlds[c][ks * 32 + kq];
            acc0 = __builtin_amdgcn_mfma_f32_16x16x32_bf16(ah, w, acc0, 0, 0, 0);
            acc1 = __builtin_amdgcn_mfma_f32_16x16x32_bf16(al, w, acc1, 0, 0, 0);
        }
        if (t > 0) {
            const __bf16* hh = hhi_p + (size_t)rowA * H_ + kq;
            const __bf16* hl = hlo_p + (size_t)rowA * H_ + kq;
            #pragma unroll
            for (int ks = 0; ks < 32; ++ks) {
                bf8v ah = *(const bf8v*)(hh + ks * 32);
                bf8v al = *(const bf8v*)(hl + ks * 32);
                bf8v w  = *(const bf8v*)&Wlds[c][IN_ + ks * 32 + kq];
                acc0 = __builtin_amdgcn_mfma_f32_16x16x32_bf16(ah, w, acc0, 0, 0, 0);
                acc1 = __builtin_amdgcn_mfma_f32_16x16x32_bf16(al, w, acc1, 0, 0, 0);
            }
        }
        f4v acc = acc0 + acc1;
        #pragma unroll
        for (int r = 0; r < 4; ++r)
            gbuf[wave * 16 + quad * 4 + r][c] = acc[r] + biasv;  // C: col=c, row=quad*4+r

        // ---- phase A2: out-proj partial for step t-1 (reads same h_{t-1}) ----
        if (t > 0) {
            f4v oac = {0.f, 0.f, 0.f, 0.f};
            #pragma unroll
            for (int kk = 0; kk < 8; ++kk) {
                int kbase = wave * 256 + kk * 32 + kq;
                bf8v ah = {}, al = {};
                if (c < 8) {   // A rows 8..15 zero (8 batches per tile)
                    ah = *(const bf8v*)&hhi_p[(size_t)(ob0 + c) * H_ + kbase];
                    al = *(const bf8v*)&hlo_p[(size_t)(ob0 + c) * H_ + kbase];
                }
                oac = __builtin_amdgcn_mfma_f32_16x16x32_bf16(ah, wof[kk], oac, 0, 0, 0);
                oac = __builtin_amdgcn_mfma_f32_16x16x32_bf16(al, wof[kk], oac, 0, 0, 0);
            }
            #pragma unroll
            for (int r = 0; r < 4; ++r)
                obuf[wave][quad * 4 + r][c] = oac[r];
        }
        __syncthreads();

        // ---- phase B: elementwise cell update, write h_t (hi+lo, write-through) ----
        {
            float gi = gbuf[bb][jo];
            float gf = gbuf[bb][4 + jo];
            float gg = gbuf[bb][8 + jo];
            float go = gbuf[bb][12 + jo];
            c_reg = sigm(gf) * c_reg + sigm(gi) * tanh_f(gg);
            float hn = sigm(go) * tanh_f(c_reg);
            __bf16 hh = (__bf16)hn;
            store_bf16_wt(&hhi_c[(size_t)bb * H_ + j0 + jo], hh);
            store_bf16_wt(&hlo_c[(size_t)bb * H_ + j0 + jo], (__bf16)(hn - (float)hh));
        }
        // ---- phase B2: reduce out-proj partials, store out[:, t-1, :] ----
        if (t > 0 && tid < 128) {
            int m = tid >> 4, cc = tid & 15;
            float v = obuf[0][m][cc] + obuf[1][m][cc] + obuf[2][m][cc] + obuf[3][m][cc]
                    + bo[oc0 + cc];
            out[(((size_t)(ob0 + m)) * T_ + (t - 1)) * OUT_ + oc0 + cc] = v;
        }

        grid_barrier(flags, t, blk);   // publish h_t; guards gbuf/obuf WAR
    }

    // ---- epilogue: out-proj for t = T-1 (h_{T-1} is in buffer 0; T even) ----
    {
        const __bf16* hhi_l = hws;
        const __bf16* hlo_l = hws + B_ * H_;
        f4v oac = {0.f, 0.f, 0.f, 0.f};
        #pragma unroll
        for (int kk = 0; kk < 8; ++kk) {
            int kbase = wave * 256 + kk * 32 + kq;
            bf8v ah = {}, al = {};
            if (c < 8) {
                ah = *(const bf8v*)&hhi_l[(size_t)(ob0 + c) * H_ + kbase];
                al = *(const bf8v*)&hlo_l[(size_t)(ob0 + c) * H_ + kbase];
            }
            oac = __builtin_amdgcn_mfma_f32_16x16x32_bf16(ah, wof[kk], oac, 0, 0, 0);
            oac = __builtin_amdgcn_mfma_f32_16x16x32_bf16(al, wof[kk], oac, 0, 0, 0);
        }
        #pragma unroll
        for (int r = 0; r < 4; ++r)
            obuf[wave][quad * 4 + r][c] = oac[r];
        __syncthreads();
        if (tid < 128) {
            int m = tid >> 4, cc = tid & 15;
            float v = obuf[0][m][cc] + obuf[1][m][cc] + obuf[2][m][cc] + obuf[3][m][cc]
                    + bo[oc0 + cc];
            out[(((size_t)(ob0 + m)) * T_ + (T_ - 1)) * OUT_ + oc0 + cc] = v;
        }
    }
}

extern "C" void kernel_launch(void* const* d_in, const int* in_sizes, int n_in,
                              void* d_out, int out_size, void* d_ws, size_t ws_size,
                              hipStream_t stream) {
    const float* xs = (const float*)d_in[0];
    const float* Wi = (const float*)d_in[1];
    const float* Wh = (const float*)d_in[2];
    const float* b  = (const float*)d_in[3];
    const float* Wo = (const float*)d_in[4];
    const float* bo = (const float*)d_in[5];
    float* out = (float*)d_out;

    // ws layout: [0,16K) flag vector (256 x 64B-padded, zeroed);
    //            [64K, +512K) h double-buffer (hi/lo bf16)
    unsigned* flags = (unsigned*)d_ws;         // flags[i*16], i = 0..255
    __bf16*   hws   = (__bf16*)((char*)d_ws + 65536);

    hipMemsetAsync(d_ws, 0, 32768, stream);    // reset flags (graph-capture safe)

    void* args[] = {(void*)&xs, (void*)&Wi, (void*)&Wh, (void*)&b,
                    (void*)&Wo, (void*)&bo, (void*)&out, (void*)&hws,
                    (void*)&flags};
    hipLaunchCooperativeKernel((void*)lstm_fused, dim3(256), dim3(256), args, 0, stream);
}